// Round 1
// baseline (675.371 us; speedup 1.0000x reference)
//
#include <hip/hip_runtime.h>
#include <hip/hip_bf16.h>

typedef float f32x4 __attribute__((ext_vector_type(4)));
typedef __bf16 bf16x8 __attribute__((ext_vector_type(8)));

__device__ __forceinline__ unsigned short f2bf(float f) {
    union { float f; unsigned int u; } v; v.f = f;
    unsigned int u = v.u;
    unsigned int r = (u + 0x7fffu + ((u >> 16) & 1u)) >> 16;
    return (unsigned short)r;
}

__device__ __forceinline__ unsigned int pack2bf(float a, float b) {
    return (unsigned int)f2bf(a) | ((unsigned int)f2bf(b) << 16);
}

// fp32 -> bf16 convert, 4 elems/thread
__global__ __launch_bounds__(256) void k_cvt(const float* __restrict__ in,
                                             unsigned short* __restrict__ out, int n4) {
    int i = blockIdx.x * 256 + threadIdx.x;
    if (i >= n4) return;
    float4 v = ((const float4*)in)[i];
    ushort4 o;
    o.x = f2bf(v.x); o.y = f2bf(v.y); o.z = f2bf(v.z); o.w = f2bf(v.w);
    ((ushort4*)out)[i] = o;
}

// C[r][e] = sum_d A[r][d]*W[e][d] + bias[e], written transposed+split-head to
// Vt[b][h][d][k] (bf16), r = b*2048+k, e = h*128+d.
// Block = 4 waves, each wave a 32x32 tile; block tile 64x64.
__global__ __launch_bounds__(256) void k_inproj(const unsigned short* __restrict__ A,
                                                const unsigned short* __restrict__ W,
                                                const float* __restrict__ bias,
                                                unsigned short* __restrict__ Vt) {
    const int K = 1024;
    int wv = threadIdx.x >> 6, lane = threadIdx.x & 63;
    int mr = lane & 15, quad = lane >> 4;
    int m0 = blockIdx.y * 64 + (wv >> 1) * 32;
    int n0 = blockIdx.x * 64 + (wv & 1) * 32;
    f32x4 acc00 = {}, acc01 = {}, acc10 = {}, acc11 = {};
    const unsigned short* ap0 = A + (size_t)(m0 + mr) * K + quad * 8;
    const unsigned short* ap1 = ap0 + 16 * K;
    const unsigned short* bp0 = W + (size_t)(n0 + mr) * K + quad * 8;
    const unsigned short* bp1 = bp0 + 16 * K;
    for (int kk = 0; kk < K; kk += 32) {
        bf16x8 a0 = *(const bf16x8*)(ap0 + kk);
        bf16x8 a1 = *(const bf16x8*)(ap1 + kk);
        bf16x8 b0 = *(const bf16x8*)(bp0 + kk);
        bf16x8 b1 = *(const bf16x8*)(bp1 + kk);
        acc00 = __builtin_amdgcn_mfma_f32_16x16x32_bf16(a0, b0, acc00, 0, 0, 0);
        acc01 = __builtin_amdgcn_mfma_f32_16x16x32_bf16(a0, b1, acc01, 0, 0, 0);
        acc10 = __builtin_amdgcn_mfma_f32_16x16x32_bf16(a1, b0, acc10, 0, 0, 0);
        acc11 = __builtin_amdgcn_mfma_f32_16x16x32_bf16(a1, b1, acc11, 0, 0, 0);
    }
    f32x4 accs[2][2] = {{acc00, acc01}, {acc10, acc11}};
    #pragma unroll
    for (int i = 0; i < 2; i++)
    #pragma unroll
    for (int j = 0; j < 2; j++) {
        int e = n0 + j * 16 + mr;                 // output feature
        int r = m0 + i * 16 + quad * 4;           // row (4 consecutive via regs)
        float be = bias[e];
        int bb = r >> 11, k = r & 2047;
        int h = e >> 7, d = e & 127;
        unsigned short* dst = Vt + ((size_t)((bb * 8 + h) * 128 + d)) * 2048 + k;
        ushort4 pk;
        pk.x = f2bf(accs[i][j][0] + be);
        pk.y = f2bf(accs[i][j][1] + be);
        pk.z = f2bf(accs[i][j][2] + be);
        pk.w = f2bf(accs[i][j][3] + be);
        *(ushort4*)dst = pk;  // k contiguous
    }
}

// out[r][e] = sum_d A[r][d]*W[e][d] + bias[e]  (fp32 out)
__global__ __launch_bounds__(256) void k_outproj(const unsigned short* __restrict__ A,
                                                 const unsigned short* __restrict__ W,
                                                 const float* __restrict__ bias,
                                                 float* __restrict__ out) {
    const int K = 1024;
    int wv = threadIdx.x >> 6, lane = threadIdx.x & 63;
    int mr = lane & 15, quad = lane >> 4;
    int m0 = blockIdx.y * 64 + (wv >> 1) * 32;
    int n0 = blockIdx.x * 64 + (wv & 1) * 32;
    f32x4 acc00 = {}, acc01 = {}, acc10 = {}, acc11 = {};
    const unsigned short* ap0 = A + (size_t)(m0 + mr) * K + quad * 8;
    const unsigned short* ap1 = ap0 + 16 * K;
    const unsigned short* bp0 = W + (size_t)(n0 + mr) * K + quad * 8;
    const unsigned short* bp1 = bp0 + 16 * K;
    for (int kk = 0; kk < K; kk += 32) {
        bf16x8 a0 = *(const bf16x8*)(ap0 + kk);
        bf16x8 a1 = *(const bf16x8*)(ap1 + kk);
        bf16x8 b0 = *(const bf16x8*)(bp0 + kk);
        bf16x8 b1 = *(const bf16x8*)(bp1 + kk);
        acc00 = __builtin_amdgcn_mfma_f32_16x16x32_bf16(a0, b0, acc00, 0, 0, 0);
        acc01 = __builtin_amdgcn_mfma_f32_16x16x32_bf16(a0, b1, acc01, 0, 0, 0);
        acc10 = __builtin_amdgcn_mfma_f32_16x16x32_bf16(a1, b0, acc10, 0, 0, 0);
        acc11 = __builtin_amdgcn_mfma_f32_16x16x32_bf16(a1, b1, acc11, 0, 0, 0);
    }
    f32x4 accs[2][2] = {{acc00, acc01}, {acc10, acc11}};
    #pragma unroll
    for (int i = 0; i < 2; i++)
    #pragma unroll
    for (int j = 0; j < 2; j++) {
        int e = n0 + j * 16 + mr;
        int r = m0 + i * 16 + quad * 4;
        float be = bias[e];
        #pragma unroll
        for (int reg = 0; reg < 4; reg++)
            out[(size_t)(r + reg) * 1024 + e] = accs[i][j][reg] + be;
    }
}

// Fused masked-softmax attention + L2-weight rescale.
// Grid: 256 blocks = (b in [0,2)) x (q-tile of 16 in [0,128)). Block: 512 thr = 8 waves.
// Wave w handles head w (M=16, N=128, K=2048 streamed in 32-chunks).
// p = adj ? exp(msg) : 0 (no max-subtraction: logits ~ N(0,1), fp32-safe).
__global__ __launch_bounds__(512, 1) void k_attn(const float* __restrict__ msg,
                                                 const int* __restrict__ adj,
                                                 const unsigned short* __restrict__ Vt,
                                                 unsigned short* __restrict__ AOS) {
    __shared__ __align__(16) float lds_msg[16 * 264];  // [m][k*8+h], stride 264 (bank pad)
    __shared__ int lds_adj[16 * 33];                   // [m][k], stride 33 (bank pad)
    __shared__ uint4 lds_p[8 * 4 * 16];                // [h][kq][m] -> 8 bf16 (A-frag layout)
    __shared__ float lds_redl[512];                    // [kq][m][h]
    __shared__ float lds_reds[512];
    __shared__ float lds_w[128];                       // [m][h]

    const int t = threadIdx.x;
    const int b = blockIdx.x >> 7;
    const int q0 = (blockIdx.x & 127) * 16;

    // exp-phase role: thread -> (head, row, k-quad), 8 k's each
    const int eh = t & 7, em = (t >> 3) & 15, ekq = t >> 7;
    // mfma-phase role
    const int wv = t >> 6, lane = t & 63, mr = lane & 15, quad = lane >> 4;
    // load-phase role
    const int lm0 = t >> 6, lrem = t & 63;   // msg float4: rows lm0 and lm0+8
    const int am = t >> 5, ak = t & 31;      // adj scalar

    const float* msg_base = msg + (size_t)(b * 2048 + q0) * 2048 * 8;
    const int* adj_base = adj + (size_t)(b * 2048 + q0) * 2048;
    const unsigned short* vt_base =
        Vt + (size_t)(b * 8 + wv) * 128 * 2048 + (size_t)mr * 2048 + quad * 8;

    float lp = 0.f, s2p = 0.f;
    f32x4 acc[8] = {};

    float4 pm0, pm1;
    int pa;
    {
        const float* p0 = msg_base + (size_t)lm0 * 16384 + lrem * 4;
        pm0 = *(const float4*)p0;
        pm1 = *(const float4*)(p0 + 8 * 16384);
        pa = adj_base[(size_t)am * 2048 + ak];
    }

    for (int kb = 0; kb < 64; kb++) {
        const int k0 = kb * 32;
        __syncthreads();  // prev iter's LDS reads done
        *(float4*)&lds_msg[lm0 * 264 + lrem * 4] = pm0;
        *(float4*)&lds_msg[(lm0 + 8) * 264 + lrem * 4] = pm1;
        lds_adj[am * 33 + ak] = pa;
        if (kb < 63) {  // prefetch next k-block (overlaps exp+mfma phases)
            const float* p0 = msg_base + (size_t)lm0 * 16384 + (k0 + 32) * 8 + lrem * 4;
            pm0 = *(const float4*)p0;
            pm1 = *(const float4*)(p0 + 8 * 16384);
            pa = adj_base[(size_t)am * 2048 + k0 + 32 + ak];
        }
        __syncthreads();
        // --- exp phase: build P in MFMA A-fragment layout ---
        {
            float p[8];
            const float* mrow = &lds_msg[em * 264 + ekq * 64 + eh];
            const int* arow = &lds_adj[em * 33 + ekq * 8];
            #pragma unroll
            for (int j = 0; j < 8; j++) {
                float x = mrow[j * 8];
                int a = arow[j];
                float pe = a ? __expf(x) : 0.f;
                p[j] = pe;
                lp += pe;
                s2p += pe * pe;
            }
            uint4 pk;
            pk.x = pack2bf(p[0], p[1]);
            pk.y = pack2bf(p[2], p[3]);
            pk.z = pack2bf(p[4], p[5]);
            pk.w = pack2bf(p[6], p[7]);
            lds_p[(eh * 4 + ekq) * 16 + em] = pk;
        }
        __syncthreads();
        // --- mfma phase: P(16x32) @ V_h(32x128) ---
        bf16x8 afrag = ((const bf16x8*)lds_p)[(wv * 4 + quad) * 16 + mr];
        const unsigned short* vp = vt_base + k0;
        #pragma unroll
        for (int nc = 0; nc < 8; nc++) {
            bf16x8 bfrag = *(const bf16x8*)(vp + (size_t)nc * 16 * 2048);
            acc[nc] = __builtin_amdgcn_mfma_f32_16x16x32_bf16(afrag, bfrag, acc[nc], 0, 0, 0);
        }
    }

    // reduce l = sum p, s2 = sum p^2 over the 4 k-quads
    lds_redl[(ekq * 16 + em) * 8 + eh] = lp;
    lds_reds[(ekq * 16 + em) * 8 + eh] = s2p;
    __syncthreads();
    if (t < 128) {
        int m = t >> 3, h = t & 7;
        float l = 0.f, s2 = 0.f;
        #pragma unroll
        for (int kq = 0; kq < 4; kq++) {
            l += lds_redl[(kq * 16 + m) * 8 + h];
            s2 += lds_reds[(kq * 16 + m) * 8 + h];
        }
        lds_w[m * 8 + h] = __fsqrt_rn(s2) / (l * l);  // sqrt(sum attn^2)/l ... /l for softmax norm
    }
    __syncthreads();

    // epilogue: scale by weight, write bf16 AOS[b][q][h*128+d]
    float wr[4];
    #pragma unroll
    for (int rix = 0; rix < 4; rix++) wr[rix] = lds_w[(quad * 4 + rix) * 8 + wv];
    unsigned short* aos_base =
        AOS + (size_t)(b * 2048 + q0 + quad * 4) * 1024 + wv * 128 + mr;
    #pragma unroll
    for (int nc = 0; nc < 8; nc++) {
        #pragma unroll
        for (int rix = 0; rix < 4; rix++) {
            aos_base[(size_t)rix * 1024 + nc * 16] = f2bf(acc[nc][rix] * wr[rix]);
        }
    }
}

extern "C" void kernel_launch(void* const* d_in, const int* in_sizes, int n_in,
                              void* d_out, int out_size, void* d_ws, size_t ws_size,
                              hipStream_t stream) {
    const float* v_inv    = (const float*)d_in[0];  // [2][2048][1024]
    const float* messages = (const float*)d_in[1];  // [2][2048][2048][8]
    const int*   adjm     = (const int*)d_in[2];    // [2][2048][2048]
    const float* in_w     = (const float*)d_in[3];  // [1024][1024]
    const float* in_b     = (const float*)d_in[4];  // [1024]
    const float* out_w    = (const float*)d_in[5];  // [1024][1024]
    const float* out_b    = (const float*)d_in[6];  // [1024]
    float* out = (float*)d_out;                     // [2][2048][1024] fp32

    char* ws = (char*)d_ws;
    unsigned short* vinv_bf = (unsigned short*)(ws);                       // 8 MB
    unsigned short* inw_bf  = (unsigned short*)(ws + (size_t)(8  << 20));  // 2 MB
    unsigned short* outw_bf = (unsigned short*)(ws + (size_t)(10 << 20));  // 2 MB
    unsigned short* Vt      = (unsigned short*)(ws + (size_t)(12 << 20));  // 8 MB [2][8][128][2048]
    unsigned short* AOS     = (unsigned short*)(ws + (size_t)(20 << 20));  // 8 MB [4096][1024]

    hipLaunchKernelGGL(k_cvt, dim3(4096), dim3(256), 0, stream, v_inv, vinv_bf, 4194304 / 4);
    hipLaunchKernelGGL(k_cvt, dim3(1024), dim3(256), 0, stream, in_w, inw_bf, 1048576 / 4);
    hipLaunchKernelGGL(k_cvt, dim3(1024), dim3(256), 0, stream, out_w, outw_bf, 1048576 / 4);
    hipLaunchKernelGGL(k_inproj, dim3(16, 64), dim3(256), 0, stream, vinv_bf, inw_bf, in_b, Vt);
    hipLaunchKernelGGL(k_attn, dim3(256), dim3(512), 0, stream, messages, adjm, Vt, AOS);
    hipLaunchKernelGGL(k_outproj, dim3(16, 64), dim3(256), 0, stream, AOS, outw_bf, out_b, out);
}

// Round 2
// 582.070 us; speedup vs baseline: 1.1603x; 1.1603x over previous
//
#include <hip/hip_runtime.h>
#include <hip/hip_bf16.h>

typedef float f32x4 __attribute__((ext_vector_type(4)));
typedef __bf16 bf16x8 __attribute__((ext_vector_type(8)));

__device__ __forceinline__ unsigned short f2bf(float f) {
    union { float f; unsigned int u; } v; v.f = f;
    unsigned int u = v.u;
    unsigned int r = (u + 0x7fffu + ((u >> 16) & 1u)) >> 16;
    return (unsigned short)r;
}
__device__ __forceinline__ float bf2f(unsigned short u) {
    union { unsigned int u; float f; } v; v.u = ((unsigned int)u) << 16;
    return v.f;
}
__device__ __forceinline__ unsigned int pack2bf(float a, float b) {
    return (unsigned int)f2bf(a) | ((unsigned int)f2bf(b) << 16);
}

// fp32 -> bf16 convert, 4 elems/thread
__global__ __launch_bounds__(256) void k_cvt(const float* __restrict__ in,
                                             unsigned short* __restrict__ out, int n4) {
    int i = blockIdx.x * 256 + threadIdx.x;
    if (i >= n4) return;
    float4 v = ((const float4*)in)[i];
    ushort4 o;
    o.x = f2bf(v.x); o.y = f2bf(v.y); o.z = f2bf(v.z); o.w = f2bf(v.w);
    ((ushort4*)out)[i] = o;
}

// ---------------------------------------------------------------------------
// LDS-staged GEMM, tile 128(M) x 64(N), BK=32, 256 thr = 4 waves (2x2).
// C[r][e] = sum_k A[r][k]*B[e][k] + bias[e].  A:[M][1024] bf16, B:[1024][1024] bf16.
// Two kernels sharing the same body, differing in epilogue.
// ---------------------------------------------------------------------------

// epilogue 0: write Vfrag (bf16, MFMA B-fragment order) for the attention kernel
// Vfrag idx8 = (((b*8+h)*64 + kb)*8 + nc)*64 + fraglane ; 8 bf16 per idx8
__global__ __launch_bounds__(256, 2) void k_gemm_in(const unsigned short* __restrict__ A,
                                                    const unsigned short* __restrict__ B,
                                                    const float* __restrict__ bias,
                                                    unsigned short* __restrict__ Vfrag) {
    __shared__ __align__(16) unsigned short As[128 * 32];
    __shared__ __align__(16) unsigned short Bs[64 * 32];
    const int t = threadIdx.x;
    const int wv = t >> 6, lane = t & 63, mr = lane & 15, quad = lane >> 4;
    const int wi = wv >> 1, wj = wv & 1;
    const int m0 = blockIdx.y * 128, n0 = blockIdx.x * 64;

    f32x4 acc[4][2] = {};
    const int ca0 = t, ca1 = t + 256, cb = t;

    uint4 pa0, pa1, pb;
    {
        pa0 = *(const uint4*)(A + (size_t)(m0 + (ca0 >> 2)) * 1024 + (ca0 & 3) * 8);
        pa1 = *(const uint4*)(A + (size_t)(m0 + (ca1 >> 2)) * 1024 + (ca1 & 3) * 8);
        pb  = *(const uint4*)(B + (size_t)(n0 + (cb  >> 2)) * 1024 + (cb  & 3) * 8);
    }
    for (int kb = 0; kb < 32; kb++) {
        __syncthreads();
        *(uint4*)&As[(ca0 >> 2) * 32 + (ca0 & 3) * 8] = pa0;
        *(uint4*)&As[(ca1 >> 2) * 32 + (ca1 & 3) * 8] = pa1;
        *(uint4*)&Bs[(cb  >> 2) * 32 + (cb  & 3) * 8] = pb;
        if (kb < 31) {
            int kk = kb * 32 + 32;
            pa0 = *(const uint4*)(A + (size_t)(m0 + (ca0 >> 2)) * 1024 + kk + (ca0 & 3) * 8);
            pa1 = *(const uint4*)(A + (size_t)(m0 + (ca1 >> 2)) * 1024 + kk + (ca1 & 3) * 8);
            pb  = *(const uint4*)(B + (size_t)(n0 + (cb  >> 2)) * 1024 + kk + (cb  & 3) * 8);
        }
        __syncthreads();
        bf16x8 af[4], bfr[2];
        #pragma unroll
        for (int i = 0; i < 4; i++)
            af[i] = *(const bf16x8*)&As[(wi * 64 + i * 16 + mr) * 32 + quad * 8];
        #pragma unroll
        for (int j = 0; j < 2; j++)
            bfr[j] = *(const bf16x8*)&Bs[(wj * 32 + j * 16 + mr) * 32 + quad * 8];
        #pragma unroll
        for (int i = 0; i < 4; i++)
        #pragma unroll
        for (int j = 0; j < 2; j++)
            acc[i][j] = __builtin_amdgcn_mfma_f32_16x16x32_bf16(af[i], bfr[j], acc[i][j], 0, 0, 0);
    }
    #pragma unroll
    for (int i = 0; i < 4; i++)
    #pragma unroll
    for (int j = 0; j < 2; j++) {
        int col = n0 + wj * 32 + j * 16 + mr;         // e
        int row0 = m0 + wi * 64 + i * 16 + quad * 4;  // r (4 consecutive via regs)
        float be = bias[col];
        int h = col >> 7, d = col & 127;
        int bb = row0 >> 11, k = row0 & 2047;
        size_t idx8 = ((((size_t)(bb * 8 + h) * 64 + (k >> 5)) * 8 + (d >> 4)) * 64
                       + ((k >> 3) & 3) * 16 + (d & 15));
        int j0 = (quad & 1) * 4;                      // k&7 base within fragment
        ushort4 pk;
        pk.x = f2bf(acc[i][j][0] + be);
        pk.y = f2bf(acc[i][j][1] + be);
        pk.z = f2bf(acc[i][j][2] + be);
        pk.w = f2bf(acc[i][j][3] + be);
        *(ushort4*)(Vfrag + idx8 * 8 + j0) = pk;
    }
}

// epilogue 1: fp32 row-major out
__global__ __launch_bounds__(256, 2) void k_gemm_out(const unsigned short* __restrict__ A,
                                                     const unsigned short* __restrict__ B,
                                                     const float* __restrict__ bias,
                                                     float* __restrict__ out) {
    __shared__ __align__(16) unsigned short As[128 * 32];
    __shared__ __align__(16) unsigned short Bs[64 * 32];
    const int t = threadIdx.x;
    const int wv = t >> 6, lane = t & 63, mr = lane & 15, quad = lane >> 4;
    const int wi = wv >> 1, wj = wv & 1;
    const int m0 = blockIdx.y * 128, n0 = blockIdx.x * 64;

    f32x4 acc[4][2] = {};
    const int ca0 = t, ca1 = t + 256, cb = t;

    uint4 pa0, pa1, pb;
    {
        pa0 = *(const uint4*)(A + (size_t)(m0 + (ca0 >> 2)) * 1024 + (ca0 & 3) * 8);
        pa1 = *(const uint4*)(A + (size_t)(m0 + (ca1 >> 2)) * 1024 + (ca1 & 3) * 8);
        pb  = *(const uint4*)(B + (size_t)(n0 + (cb  >> 2)) * 1024 + (cb  & 3) * 8);
    }
    for (int kb = 0; kb < 32; kb++) {
        __syncthreads();
        *(uint4*)&As[(ca0 >> 2) * 32 + (ca0 & 3) * 8] = pa0;
        *(uint4*)&As[(ca1 >> 2) * 32 + (ca1 & 3) * 8] = pa1;
        *(uint4*)&Bs[(cb  >> 2) * 32 + (cb  & 3) * 8] = pb;
        if (kb < 31) {
            int kk = kb * 32 + 32;
            pa0 = *(const uint4*)(A + (size_t)(m0 + (ca0 >> 2)) * 1024 + kk + (ca0 & 3) * 8);
            pa1 = *(const uint4*)(A + (size_t)(m0 + (ca1 >> 2)) * 1024 + kk + (ca1 & 3) * 8);
            pb  = *(const uint4*)(B + (size_t)(n0 + (cb  >> 2)) * 1024 + kk + (cb  & 3) * 8);
        }
        __syncthreads();
        bf16x8 af[4], bfr[2];
        #pragma unroll
        for (int i = 0; i < 4; i++)
            af[i] = *(const bf16x8*)&As[(wi * 64 + i * 16 + mr) * 32 + quad * 8];
        #pragma unroll
        for (int j = 0; j < 2; j++)
            bfr[j] = *(const bf16x8*)&Bs[(wj * 32 + j * 16 + mr) * 32 + quad * 8];
        #pragma unroll
        for (int i = 0; i < 4; i++)
        #pragma unroll
        for (int j = 0; j < 2; j++)
            acc[i][j] = __builtin_amdgcn_mfma_f32_16x16x32_bf16(af[i], bfr[j], acc[i][j], 0, 0, 0);
    }
    #pragma unroll
    for (int i = 0; i < 4; i++)
    #pragma unroll
    for (int j = 0; j < 2; j++) {
        int col = n0 + wj * 32 + j * 16 + mr;
        int row0 = m0 + wi * 64 + i * 16 + quad * 4;
        float be = bias[col];
        #pragma unroll
        for (int reg = 0; reg < 4; reg++)
            out[(size_t)(row0 + reg) * 1024 + col] = acc[i][j][reg] + be;
    }
}

// ---------------------------------------------------------------------------
// Fused masked-softmax attention, K-split by 4.
// Grid: (256, 4): x = (b, q-tile of 16), y = ks (k range of 512). Block 512 = 8 waves.
// Wave w = head w: P(16x32) @ V(32x128) per k-block; 16 k-blocks per ks.
// Outputs: Ppart bf16 [ks][bq][1024], Lpart/Spart fp32 [ks][bq][8].
// ---------------------------------------------------------------------------
__global__ __launch_bounds__(512, 8) void k_attn(const float* __restrict__ msg,
                                                 const int* __restrict__ adj,
                                                 const unsigned short* __restrict__ Vfrag,
                                                 unsigned short* __restrict__ Ppart,
                                                 float* __restrict__ Lpart,
                                                 float* __restrict__ Spart) {
    __shared__ __align__(16) float lds_msg[16 * 264];  // [m][k*8+h], stride 264 (bank pad)
    __shared__ int lds_adj[16 * 33];                   // [m][k], stride 33 (bank pad)
    __shared__ uint4 lds_p[8 * 4 * 16];                // [h][kq][m] -> 8 bf16 (A-frag layout)
    __shared__ float lds_redl[512];                    // [kq][m][h]
    __shared__ float lds_reds[512];

    const int t = threadIdx.x;
    const int b = blockIdx.x >> 7;
    const int q0 = (blockIdx.x & 127) * 16;
    const int ks = blockIdx.y;

    const int eh = t & 7, em = (t >> 3) & 15, ekq = t >> 7;  // exp-phase role
    const int wv = t >> 6, lane = t & 63, mr = lane & 15, quad = lane >> 4;  // mfma role
    const int lm0 = t >> 6, lrem = t & 63;   // msg float4 loader: rows lm0, lm0+8
    const int am = t >> 5, ak = t & 31;      // adj loader

    const float* msg_base = msg + ((size_t)(b * 2048 + q0) * 2048 + ks * 512) * 8;
    const int* adj_base = adj + (size_t)(b * 2048 + q0) * 2048 + ks * 512;
    // Vfrag: (((b*8+h)*64 + kbg)*8 + nc)*64 + lane, 8 bf16 each; lane-contiguous.
    const unsigned short* vf_base =
        Vfrag + ((((size_t)(b * 8 + wv) * 64 + ks * 16) * 8) * 64 + lane) * 8;

    float lp = 0.f, s2p = 0.f;
    f32x4 acc[8] = {};

    float4 pm0, pm1;
    int pa;
    {
        const float* p0 = msg_base + (size_t)lm0 * 16384 + lrem * 4;
        pm0 = *(const float4*)p0;
        pm1 = *(const float4*)(p0 + 8 * 16384);
        pa = adj_base[(size_t)am * 2048 + ak];
    }

    for (int kb = 0; kb < 16; kb++) {
        const int k0 = kb * 32;
        __syncthreads();  // prev iter's LDS reads done
        *(float4*)&lds_msg[lm0 * 264 + lrem * 4] = pm0;
        *(float4*)&lds_msg[(lm0 + 8) * 264 + lrem * 4] = pm1;
        lds_adj[am * 33 + ak] = pa;
        if (kb < 15) {  // prefetch next k-block
            const float* p0 = msg_base + (size_t)lm0 * 16384 + (k0 + 32) * 8 + lrem * 4;
            pm0 = *(const float4*)p0;
            pm1 = *(const float4*)(p0 + 8 * 16384);
            pa = adj_base[(size_t)am * 2048 + k0 + 32 + ak];
        }
        __syncthreads();
        // --- exp phase: build P in MFMA A-fragment layout ---
        {
            float p[8];
            const float* mrow = &lds_msg[em * 264 + ekq * 64 + eh];
            const int* arow = &lds_adj[em * 33 + ekq * 8];
            #pragma unroll
            for (int j = 0; j < 8; j++) {
                float x = mrow[j * 8];
                int a = arow[j];
                float pe = a ? __expf(x) : 0.f;
                p[j] = pe;
                lp += pe;
                s2p += pe * pe;
            }
            uint4 pk;
            pk.x = pack2bf(p[0], p[1]);
            pk.y = pack2bf(p[2], p[3]);
            pk.z = pack2bf(p[4], p[5]);
            pk.w = pack2bf(p[6], p[7]);
            lds_p[(eh * 4 + ekq) * 16 + em] = pk;
        }
        __syncthreads();
        // --- mfma phase: coalesced Vfrag B loads (1 KB/instr) ---
        bf16x8 afrag = ((const bf16x8*)lds_p)[(wv * 4 + quad) * 16 + mr];
        const unsigned short* vp = vf_base + (size_t)kb * 8 * 64 * 8;
        #pragma unroll
        for (int nc = 0; nc < 8; nc++) {
            bf16x8 bfrag = *(const bf16x8*)(vp + (size_t)nc * 64 * 8);
            acc[nc] = __builtin_amdgcn_mfma_f32_16x16x32_bf16(afrag, bfrag, acc[nc], 0, 0, 0);
        }
    }

    // reduce partial l, s2 over the 4 k-quads
    lds_redl[(ekq * 16 + em) * 8 + eh] = lp;
    lds_reds[(ekq * 16 + em) * 8 + eh] = s2p;
    __syncthreads();
    if (t < 128) {
        int m = t >> 3, h = t & 7;
        float l = 0.f, s2 = 0.f;
        #pragma unroll
        for (int kq = 0; kq < 4; kq++) {
            l += lds_redl[(kq * 16 + m) * 8 + h];
            s2 += lds_reds[(kq * 16 + m) * 8 + h];
        }
        size_t idx = ((size_t)ks * 4096 + b * 2048 + q0 + m) * 8 + h;
        Lpart[idx] = l;
        Spart[idx] = s2;
    }

    // write bf16 partial PV
    unsigned short* pp_base =
        Ppart + ((size_t)ks * 4096 + b * 2048 + q0 + quad * 4) * 1024 + wv * 128 + mr;
    #pragma unroll
    for (int nc = 0; nc < 8; nc++) {
        #pragma unroll
        for (int rix = 0; rix < 4; rix++)
            pp_base[(size_t)rix * 1024 + nc * 16] = f2bf(acc[nc][rix]);
    }
}

// Combine K-split partials: AOS[bq][e] = (sum_ks Ppart) * sqrt(sum s2)/(sum l)^2
__global__ __launch_bounds__(256) void k_combine(const unsigned short* __restrict__ Ppart,
                                                 const float* __restrict__ Lpart,
                                                 const float* __restrict__ Spart,
                                                 unsigned short* __restrict__ AOS) {
    __shared__ float w8[8];
    const int t = threadIdx.x;
    const size_t bq = blockIdx.x;
    if (t < 8) {
        float l = 0.f, s2 = 0.f;
        #pragma unroll
        for (int ks = 0; ks < 4; ks++) {
            size_t idx = ((size_t)ks * 4096 + bq) * 8 + t;
            l += Lpart[idx];
            s2 += Spart[idx];
        }
        w8[t] = __fsqrt_rn(s2) / (l * l);
    }
    __syncthreads();
    const int c0 = t * 4;
    const float w = w8[c0 >> 7];
    float s0 = 0.f, s1 = 0.f, s2 = 0.f, s3 = 0.f;
    #pragma unroll
    for (int ks = 0; ks < 4; ks++) {
        ushort4 p = *(const ushort4*)(Ppart + ((size_t)ks * 4096 + bq) * 1024 + c0);
        s0 += bf2f(p.x); s1 += bf2f(p.y); s2 += bf2f(p.z); s3 += bf2f(p.w);
    }
    ushort4 o;
    o.x = f2bf(s0 * w); o.y = f2bf(s1 * w); o.z = f2bf(s2 * w); o.w = f2bf(s3 * w);
    *(ushort4*)(AOS + bq * 1024 + c0) = o;
}

extern "C" void kernel_launch(void* const* d_in, const int* in_sizes, int n_in,
                              void* d_out, int out_size, void* d_ws, size_t ws_size,
                              hipStream_t stream) {
    const float* v_inv    = (const float*)d_in[0];  // [2][2048][1024]
    const float* messages = (const float*)d_in[1];  // [2][2048][2048][8]
    const int*   adjm     = (const int*)d_in[2];    // [2][2048][2048]
    const float* in_w     = (const float*)d_in[3];  // [1024][1024]
    const float* in_b     = (const float*)d_in[4];  // [1024]
    const float* out_w    = (const float*)d_in[5];  // [1024][1024]
    const float* out_b    = (const float*)d_in[6];  // [1024]
    float* out = (float*)d_out;                     // [2][2048][1024] fp32

    char* ws = (char*)d_ws;
    unsigned short* vinv_bf = (unsigned short*)(ws);                        // 8 MB
    unsigned short* inw_bf  = (unsigned short*)(ws + (size_t)(8  << 20));   // 2 MB
    unsigned short* outw_bf = (unsigned short*)(ws + (size_t)(10 << 20));   // 2 MB
    unsigned short* Vfrag   = (unsigned short*)(ws + (size_t)(12 << 20));   // 8 MB
    unsigned short* AOS     = (unsigned short*)(ws + (size_t)(20 << 20));   // 8 MB
    unsigned short* Ppart   = (unsigned short*)(ws + (size_t)(28 << 20));   // 32 MB
    float*          Lpart   = (float*)(ws + (size_t)(60 << 20));            // 512 KB
    float*          Spart   = (float*)(ws + (size_t)(60 << 20) + (512 << 10)); // 512 KB

    hipLaunchKernelGGL(k_cvt, dim3(4096), dim3(256), 0, stream, v_inv, vinv_bf, 4194304 / 4);
    hipLaunchKernelGGL(k_cvt, dim3(1024), dim3(256), 0, stream, in_w, inw_bf, 1048576 / 4);
    hipLaunchKernelGGL(k_cvt, dim3(1024), dim3(256), 0, stream, out_w, outw_bf, 1048576 / 4);
    hipLaunchKernelGGL(k_gemm_in, dim3(16, 32), dim3(256), 0, stream, vinv_bf, inw_bf, in_b, Vfrag);
    hipLaunchKernelGGL(k_attn, dim3(256, 4), dim3(512), 0, stream, messages, adjm, Vfrag,
                       Ppart, Lpart, Spart);
    hipLaunchKernelGGL(k_combine, dim3(4096), dim3(256), 0, stream, Ppart, Lpart, Spart, AOS);
    hipLaunchKernelGGL(k_gemm_out, dim3(16, 32), dim3(256), 0, stream, AOS, outw_bf, out_b, out);
}

// Round 4
// 477.710 us; speedup vs baseline: 1.4138x; 1.2185x over previous
//
#include <hip/hip_runtime.h>
#include <hip/hip_bf16.h>

typedef float f32x4 __attribute__((ext_vector_type(4)));
typedef __bf16 bf16x8 __attribute__((ext_vector_type(8)));

__device__ __forceinline__ unsigned short f2bf(float f) {
    union { float f; unsigned int u; } v; v.f = f;
    unsigned int u = v.u;
    unsigned int r = (u + 0x7fffu + ((u >> 16) & 1u)) >> 16;
    return (unsigned short)r;
}
__device__ __forceinline__ float bf2f(unsigned short u) {
    union { unsigned int u; float f; } v; v.u = ((unsigned int)u) << 16;
    return v.f;
}

// Raw workgroup barrier WITHOUT the vmcnt(0) drain __syncthreads() emits.
// 0xC07F = vmcnt(63) | expcnt(7) | lgkmcnt(0): wait only for LDS ops, leave
// global prefetch loads in flight across the barrier (m139-validated recipe).
__device__ __forceinline__ void block_sync_lgkm() {
    __asm__ __volatile__("" ::: "memory");
    __builtin_amdgcn_s_waitcnt(0xC07F);
    __builtin_amdgcn_s_barrier();
    __asm__ __volatile__("" ::: "memory");
}

// fp32 -> bf16 convert, 4 elems/thread
__global__ __launch_bounds__(256) void k_cvt(const float* __restrict__ in,
                                             unsigned short* __restrict__ out, int n4) {
    int i = blockIdx.x * 256 + threadIdx.x;
    if (i >= n4) return;
    float4 v = ((const float4*)in)[i];
    ushort4 o;
    o.x = f2bf(v.x); o.y = f2bf(v.y); o.z = f2bf(v.z); o.w = f2bf(v.w);
    ((ushort4*)out)[i] = o;
}

// ---------------------------------------------------------------------------
// GEMM 1: proj[r][e] = sum_d v_inv[r][d]*in_w[e][d] + in_b[e], written as
// Vfrag (bf16 MFMA B-fragment order) for the attention kernel.
// Tile 128(M=r) x 64(N=e), BK=32, 256 thr = 4 waves (2x2), double-buffered
// LDS, single raw barrier per K-iter, register prefetch of next tile.
// ---------------------------------------------------------------------------
__global__ __launch_bounds__(256, 4) void k_gemm_in(const unsigned short* __restrict__ A,
                                                    const unsigned short* __restrict__ B,
                                                    const float* __restrict__ bias,
                                                    unsigned short* __restrict__ Vfrag) {
    __shared__ __align__(16) unsigned short As[2][128 * 32];
    __shared__ __align__(16) unsigned short Bs[2][64 * 32];
    const int t = threadIdx.x;
    const int wv = t >> 6, lane = t & 63, mr = lane & 15, quad = lane >> 4;
    const int wi = wv >> 1, wj = wv & 1;
    const int m0 = blockIdx.y * 128, n0 = blockIdx.x * 64;

    f32x4 acc[4][2] = {};
    const int ra0 = t >> 2, ra1 = (t >> 2) + 64, rb = t >> 2;
    const int koff = (t & 3) * 8;

    uint4 pa0 = *(const uint4*)(A + (size_t)(m0 + ra0) * 1024 + koff);
    uint4 pa1 = *(const uint4*)(A + (size_t)(m0 + ra1) * 1024 + koff);
    uint4 pb  = *(const uint4*)(B + (size_t)(n0 + rb)  * 1024 + koff);

    for (int kb = 0; kb < 32; kb++) {
        unsigned short* as = As[kb & 1];
        unsigned short* bs = Bs[kb & 1];
        *(uint4*)&as[ra0 * 32 + koff] = pa0;
        *(uint4*)&as[ra1 * 32 + koff] = pa1;
        *(uint4*)&bs[rb  * 32 + koff] = pb;
        if (kb < 31) {
            int kk = (kb + 1) * 32 + koff;
            pa0 = *(const uint4*)(A + (size_t)(m0 + ra0) * 1024 + kk);
            pa1 = *(const uint4*)(A + (size_t)(m0 + ra1) * 1024 + kk);
            pb  = *(const uint4*)(B + (size_t)(n0 + rb)  * 1024 + kk);
        }
        block_sync_lgkm();
        bf16x8 af[4], bf[2];
        #pragma unroll
        for (int i = 0; i < 4; i++)
            af[i] = *(const bf16x8*)&as[(wi * 64 + i * 16 + mr) * 32 + quad * 8];
        #pragma unroll
        for (int j = 0; j < 2; j++)
            bf[j] = *(const bf16x8*)&bs[(wj * 32 + j * 16 + mr) * 32 + quad * 8];
        #pragma unroll
        for (int i = 0; i < 4; i++)
        #pragma unroll
        for (int j = 0; j < 2; j++)
            acc[i][j] = __builtin_amdgcn_mfma_f32_16x16x32_bf16(af[i], bf[j], acc[i][j], 0, 0, 0);
    }
    // epilogue: coalesced Vfrag fragment store (512 B per wave-instr)
    #pragma unroll
    for (int i = 0; i < 4; i++)
    #pragma unroll
    for (int j = 0; j < 2; j++) {
        int col = n0 + wj * 32 + j * 16 + mr;         // e
        int row0 = m0 + wi * 64 + i * 16 + quad * 4;  // r
        float be = bias[col];
        int h = col >> 7, d = col & 127;
        int bb = row0 >> 11, k = row0 & 2047;
        size_t idx8 = ((((size_t)(bb * 8 + h) * 64 + (k >> 5)) * 8 + (d >> 4)) * 64
                       + ((k >> 3) & 3) * 16 + (d & 15));
        int j0 = (quad & 1) * 4;
        ushort4 pk;
        pk.x = f2bf(acc[i][j][0] + be);
        pk.y = f2bf(acc[i][j][1] + be);
        pk.z = f2bf(acc[i][j][2] + be);
        pk.w = f2bf(acc[i][j][3] + be);
        *(ushort4*)(Vfrag + idx8 * 8 + j0) = pk;
    }
}

// ---------------------------------------------------------------------------
// GEMM 2: out[r][e] = sum_d AOS[r][d]*out_w[e][d] + out_b[e] (fp32 out).
// Operands SWAPPED vs gemm_in: A-frag = out_w rows (M=e, 128), B-frag = AOS
// rows (N=r, 64). C/D layout row=quad*4+reg => lane holds 4 consecutive e at
// fixed r => aligned float4 stores (64 B full sectors, no write amp).
// ---------------------------------------------------------------------------
__global__ __launch_bounds__(256, 4) void k_gemm_out(const unsigned short* __restrict__ W,
                                                     const unsigned short* __restrict__ AOS,
                                                     const float* __restrict__ bias,
                                                     float* __restrict__ out) {
    __shared__ __align__(16) unsigned short As[2][128 * 32];
    __shared__ __align__(16) unsigned short Bs[2][64 * 32];
    const int t = threadIdx.x;
    const int wv = t >> 6, lane = t & 63, mr = lane & 15, quad = lane >> 4;
    const int wi = wv >> 1, wj = wv & 1;
    const int e0 = blockIdx.y * 128, r0 = blockIdx.x * 64;

    f32x4 acc[4][2] = {};
    const int ra0 = t >> 2, ra1 = (t >> 2) + 64, rb = t >> 2;
    const int koff = (t & 3) * 8;

    uint4 pa0 = *(const uint4*)(W   + (size_t)(e0 + ra0) * 1024 + koff);
    uint4 pa1 = *(const uint4*)(W   + (size_t)(e0 + ra1) * 1024 + koff);
    uint4 pb  = *(const uint4*)(AOS + (size_t)(r0 + rb)  * 1024 + koff);

    for (int kb = 0; kb < 32; kb++) {
        unsigned short* as = As[kb & 1];
        unsigned short* bs = Bs[kb & 1];
        *(uint4*)&as[ra0 * 32 + koff] = pa0;
        *(uint4*)&as[ra1 * 32 + koff] = pa1;
        *(uint4*)&bs[rb  * 32 + koff] = pb;
        if (kb < 31) {
            int kk = (kb + 1) * 32 + koff;
            pa0 = *(const uint4*)(W   + (size_t)(e0 + ra0) * 1024 + kk);
            pa1 = *(const uint4*)(W   + (size_t)(e0 + ra1) * 1024 + kk);
            pb  = *(const uint4*)(AOS + (size_t)(r0 + rb)  * 1024 + kk);
        }
        block_sync_lgkm();
        bf16x8 af[4], bf[2];
        #pragma unroll
        for (int i = 0; i < 4; i++)
            af[i] = *(const bf16x8*)&as[(wi * 64 + i * 16 + mr) * 32 + quad * 8];
        #pragma unroll
        for (int j = 0; j < 2; j++)
            bf[j] = *(const bf16x8*)&bs[(wj * 32 + j * 16 + mr) * 32 + quad * 8];
        #pragma unroll
        for (int i = 0; i < 4; i++)
        #pragma unroll
        for (int j = 0; j < 2; j++)
            acc[i][j] = __builtin_amdgcn_mfma_f32_16x16x32_bf16(af[i], bf[j], acc[i][j], 0, 0, 0);
    }
    #pragma unroll
    for (int i = 0; i < 4; i++)
    #pragma unroll
    for (int j = 0; j < 2; j++) {
        int r_ = r0 + wj * 32 + j * 16 + mr;                // col = lane&15 -> r
        int e_ = e0 + wi * 64 + i * 16 + quad * 4;          // row = quad*4+reg -> e
        float4 bv = *(const float4*)&bias[e_];
        float4 o;
        o.x = acc[i][j][0] + bv.x;
        o.y = acc[i][j][1] + bv.y;
        o.z = acc[i][j][2] + bv.z;
        o.w = acc[i][j][3] + bv.w;
        *(float4*)&out[(size_t)r_ * 1024 + e_] = o;
    }
}

// ---------------------------------------------------------------------------
// Fused masked-softmax attention, K-split by 4, zero-LDS data path for msg:
// each thread loads msg/adj for its (2 q-rows, 1 k, 4 heads), computes
// p = adj ? exp(msg) : 0 at load time, writes p directly into a swizzled
// A-fragment LDS buffer. One raw barrier per K-iter; msg/adj/Vfrag all
// register-prefetched one full iteration ahead (fine-grained vmcnt waits).
// Grid (256,4): x=(b,q-tile16), y=ks. Block 512 = 8 waves; wave = head.
// ---------------------------------------------------------------------------
__global__ __launch_bounds__(512, 4) void k_attn(const float* __restrict__ msg,
                                                 const int* __restrict__ adj,
                                                 const unsigned short* __restrict__ Vfrag,
                                                 unsigned short* __restrict__ Ppart,
                                                 float* __restrict__ Lpart,
                                                 float* __restrict__ Spart) {
    // P in A-frag layout, XOR-swizzled: uint4 slot s*16 + (m ^ (s&15)),
    // s = h*4 + (k>>3), m = q-row, j = k&7 within the slot. Double-buffered.
    __shared__ __align__(16) unsigned short lds_p[2][4096];  // 2 x 8 KB

    const int t = threadIdx.x;
    const int b = blockIdx.x >> 7;
    const int q0 = (blockIdx.x & 127) * 16;
    const int ks = blockIdx.y;

    const int wv = t >> 6, lane = t & 63, mr = lane & 15, quad = lane >> 4;
    const int kl = lane >> 1;            // k_local 0..31
    const int h0 = (lane & 1) * 4;       // this thread's 4 heads
    const int lm0 = wv;                  // q-rows lm0 and lm0+8

    const float* msg_base = msg + ((size_t)(b * 2048 + q0) * 2048 + ks * 512) * 8;
    const int* adj_base = adj + (size_t)(b * 2048 + q0) * 2048 + ks * 512;
    const unsigned short* vf_base =
        Vfrag + ((((size_t)(b * 8 + wv) * 64 + ks * 16) * 8) * 64 + lane) * 8;

    const float* mp0 = msg_base + (size_t)lm0 * 16384 + kl * 8 + h0;
    const float* mp1 = mp0 + 8 * 16384;
    const int* ap0 = adj_base + lm0 * 2048 + kl;
    const int* ap1 = ap0 + 8 * 2048;

    // prefetch kb=0
    float4 m0r = *(const float4*)mp0;
    float4 m1r = *(const float4*)mp1;
    int a0r = ap0[0], a1r = ap1[0];
    bf16x8 vfR[8];
    #pragma unroll
    for (int nc = 0; nc < 8; nc++) vfR[nc] = *(const bf16x8*)(vf_base + nc * 512);

    float laccs[2][4] = {}, saccs[2][4] = {};
    f32x4 acc[8] = {};

    const int sr = wv * 4 + quad;  // read-side swizzle slot
    const int afrag_off = (sr * 16 + (mr ^ (sr & 15))) * 8;

    for (int kb = 0; kb < 16; kb++) {
        unsigned short* pbuf = lds_p[kb & 1];
        // --- exp at load time, write p into A-frag LDS ---
        float px[2][4] = {{m0r.x, m0r.y, m0r.z, m0r.w}, {m1r.x, m1r.y, m1r.z, m1r.w}};
        int av[2] = {a0r, a1r};
        #pragma unroll
        for (int qi = 0; qi < 2; qi++) {
            #pragma unroll
            for (int hj = 0; hj < 4; hj++) {
                float pe = av[qi] ? __expf(px[qi][hj]) : 0.f;
                laccs[qi][hj] += pe;
                saccs[qi][hj] += pe * pe;
                int s = (h0 + hj) * 4 + (kl >> 3);
                int m = lm0 + qi * 8;
                pbuf[(s * 16 + (m ^ (s & 15))) * 8 + (kl & 7)] = f2bf(pe);
            }
        }
        // --- prefetch msg/adj for kb+1 (stays in flight across barrier) ---
        if (kb < 15) {
            m0r = *(const float4*)(mp0 + (kb + 1) * 256);
            m1r = *(const float4*)(mp1 + (kb + 1) * 256);
            a0r = ap0[(kb + 1) * 32];
            a1r = ap1[(kb + 1) * 32];
        }
        block_sync_lgkm();
        // --- MFMA: P(16x32) @ V(32x128) with prefetched Vfrag regs ---
        bf16x8 afrag = *(const bf16x8*)&pbuf[afrag_off];
        #pragma unroll
        for (int nc = 0; nc < 8; nc++)
            acc[nc] = __builtin_amdgcn_mfma_f32_16x16x32_bf16(afrag, vfR[nc], acc[nc], 0, 0, 0);
        // --- prefetch Vfrag for kb+1 ---
        if (kb < 15) {
            const unsigned short* vp = vf_base + (size_t)(kb + 1) * 4096;
            #pragma unroll
            for (int nc = 0; nc < 8; nc++) vfR[nc] = *(const bf16x8*)(vp + nc * 512);
        }
    }

    // --- reduce partial l, s2 across lanes sharing (q,h): parity-preserving butterflies ---
    #pragma unroll
    for (int qi = 0; qi < 2; qi++)
    #pragma unroll
    for (int hj = 0; hj < 4; hj++) {
        float l = laccs[qi][hj], s = saccs[qi][hj];
        #pragma unroll
        for (int mdist = 2; mdist <= 32; mdist <<= 1) {
            l += __shfl_xor(l, mdist, 64);
            s += __shfl_xor(s, mdist, 64);
        }
        laccs[qi][hj] = l; saccs[qi][hj] = s;
    }
    if (lane < 2) {
        int hbase = lane * 4;
        #pragma unroll
        for (int qi = 0; qi < 2; qi++) {
            size_t ridx = ((size_t)ks * 4096 + b * 2048 + q0 + wv + qi * 8) * 8 + hbase;
            #pragma unroll
            for (int hj = 0; hj < 4; hj++) {
                Lpart[ridx + hj] = laccs[qi][hj];
                Spart[ridx + hj] = saccs[qi][hj];
            }
        }
    }

    // --- epilogue: coalesced fragment-layout dump (512 B per wave-instr) ---
    size_t cbase = ((((size_t)ks * 256 + blockIdx.x) * 8 + wv) * 8) * 64 + lane;
    #pragma unroll
    for (int nc = 0; nc < 8; nc++) {
        ushort4 pk;
        pk.x = f2bf(acc[nc][0]);
        pk.y = f2bf(acc[nc][1]);
        pk.z = f2bf(acc[nc][2]);
        pk.w = f2bf(acc[nc][3]);
        *(ushort4*)(Ppart + (cbase + (size_t)nc * 64) * 4) = pk;
    }
}

// ---------------------------------------------------------------------------
// Combine K-split partials + weight rescale + transpose to row-major AOS.
// Grid 256 = (b, q-tile); block 512.
// ---------------------------------------------------------------------------
__global__ __launch_bounds__(512) void k_combine(const unsigned short* __restrict__ Ppart,
                                                 const float* __restrict__ Lpart,
                                                 const float* __restrict__ Spart,
                                                 unsigned short* __restrict__ AOS) {
    __shared__ float lds_w[128];                         // [q][h]
    __shared__ __align__(16) unsigned short lds_t[16 * 1032];  // [q][e] pad 8
    const int t = threadIdx.x;
    const int bx = blockIdx.x;
    const int b = bx >> 7, q0 = (bx & 127) * 16;

    if (t < 128) {
        int q = t >> 3, h = t & 7;
        float l = 0.f, s2 = 0.f;
        #pragma unroll
        for (int ks = 0; ks < 4; ks++) {
            size_t idx = ((size_t)ks * 4096 + b * 2048 + q0 + q) * 8 + h;
            l += Lpart[idx];
            s2 += Spart[idx];
        }
        lds_w[t] = __fsqrt_rn(s2) / (l * l);
    }
    __syncthreads();
    #pragma unroll
    for (int p = 0; p < 8; p++) {
        int u = p * 512 + t;
        int lane = u & 63, nc = (u >> 6) & 7, wvp = u >> 9;
        int mr = lane & 15, quad = lane >> 4;
        float s[4] = {};
        #pragma unroll
        for (int ks = 0; ks < 4; ks++) {
            ushort4 pk = *(const ushort4*)(Ppart +
                (((((size_t)ks * 256 + bx) * 8 + wvp) * 8 + nc) * 64 + lane) * 4);
            s[0] += bf2f(pk.x); s[1] += bf2f(pk.y); s[2] += bf2f(pk.z); s[3] += bf2f(pk.w);
        }
        int e = wvp * 128 + nc * 16 + mr;
        #pragma unroll
        for (int rix = 0; rix < 4; rix++) {
            int q = quad * 4 + rix;
            lds_t[q * 1032 + e] = f2bf(s[rix] * lds_w[q * 8 + wvp]);
        }
    }
    __syncthreads();
    #pragma unroll
    for (int p = 0; p < 4; p++) {
        int le = (p * 512 + t) * 8;
        int q = le >> 10, e = le & 1023;
        uint4 v = *(const uint4*)&lds_t[q * 1032 + e];
        *(uint4*)(AOS + (size_t)(b * 2048 + q0 + q) * 1024 + e) = v;
    }
}

extern "C" void kernel_launch(void* const* d_in, const int* in_sizes, int n_in,
                              void* d_out, int out_size, void* d_ws, size_t ws_size,
                              hipStream_t stream) {
    const float* v_inv    = (const float*)d_in[0];  // [2][2048][1024]
    const float* messages = (const float*)d_in[1];  // [2][2048][2048][8]
    const int*   adjm     = (const int*)d_in[2];    // [2][2048][2048]
    const float* in_w     = (const float*)d_in[3];  // [1024][1024]
    const float* in_b     = (const float*)d_in[4];  // [1024]
    const float* out_w    = (const float*)d_in[5];  // [1024][1024]
    const float* out_b    = (const float*)d_in[6];  // [1024]
    float* out = (float*)d_out;                     // [2][2048][1024] fp32

    char* ws = (char*)d_ws;
    unsigned short* vinv_bf = (unsigned short*)(ws);                        // 8 MB
    unsigned short* inw_bf  = (unsigned short*)(ws + (size_t)(8  << 20));   // 2 MB
    unsigned short* outw_bf = (unsigned short*)(ws + (size_t)(10 << 20));   // 2 MB
    unsigned short* Vfrag   = (unsigned short*)(ws + (size_t)(12 << 20));   // 8 MB
    unsigned short* AOS     = (unsigned short*)(ws + (size_t)(20 << 20));   // 8 MB
    unsigned short* Ppart   = (unsigned short*)(ws + (size_t)(28 << 20));   // 32 MB
    float*          Lpart   = (float*)(ws + (size_t)(60 << 20));            // 512 KB
    float*          Spart   = (float*)(ws + (size_t)(60 << 20) + (512 << 10)); // 512 KB

    hipLaunchKernelGGL(k_cvt, dim3(4096), dim3(256), 0, stream, v_inv, vinv_bf, 4194304 / 4);
    hipLaunchKernelGGL(k_cvt, dim3(1024), dim3(256), 0, stream, in_w, inw_bf, 1048576 / 4);
    hipLaunchKernelGGL(k_cvt, dim3(1024), dim3(256), 0, stream, out_w, outw_bf, 1048576 / 4);
    hipLaunchKernelGGL(k_gemm_in, dim3(16, 32), dim3(256), 0, stream, vinv_bf, inw_bf, in_b, Vfrag);
    hipLaunchKernelGGL(k_attn, dim3(256, 4), dim3(512), 0, stream, messages, adjm, Vfrag,
                       Ppart, Lpart, Spart);
    hipLaunchKernelGGL(k_combine, dim3(256), dim3(512), 0, stream, Ppart, Lpart, Spart, AOS);
    // R3 BUG FIX: k_gemm_out signature is (W, AOS, bias, out) — pass outw_bf first.
    hipLaunchKernelGGL(k_gemm_out, dim3(64, 8), dim3(256), 0, stream, outw_bf, AOS, out_b, out);
}